// Round 1
// baseline (5484.887 us; speedup 1.0000x reference)
//
#include <hip/hip_runtime.h>
#include <math.h>

// Problem constants (B,S,H)=(4,1024,4096), NH=32, NKV=8, HD=128, LEVEL=256
#define B_   4
#define S_   1024
#define H_   4096
#define NH_  32
#define NKV_ 8
#define HD_  128
#define M_   (B_*S_)          // 4096 rows (b*S+s)
#define LDQKV 6144            // qkv ws row: [q 4096 | k 1024 | v 1024]
#define VOFF (H_ + NKV_*HD_)  // 5120
#define SCALING 0.08838834764831845f  // HD**-0.5, rounded to f32 like jnp

// lsq_quant forward: s_sc == s, xq == round(clip(x/s,qn,qp)); rintf = round-half-even (matches jnp.round)
__device__ __forceinline__ float lsq_sym(float x, float s) {
  float xs = x / s;
  xs = fminf(fmaxf(xs, -128.0f), 127.0f);
  return rintf(xs) * s;
}
__device__ __forceinline__ float lsq_asym(float x, float s) {
  float xs = x / s;
  xs = fminf(fmaxf(xs, 0.0f), 255.0f);
  return rintf(xs) * s;
}

// C[M,N] = A[M,K] * B[N,K]^T   (both K-major, "NT").  128x128 tile, 256 thr, 8x8/thread.
// EPI: 0 = raw store, 1 = lsq_sym(s) epilogue.
template<int EPI>
__global__ __launch_bounds__(256)
void gemm_nt(const float* __restrict__ A, int lda,
             const float* __restrict__ Bm, int ldb,
             float* __restrict__ C, int ldc, int K,
             const float* __restrict__ sptr)
{
  __shared__ float As[16][132];  // [k][m], +4 pad
  __shared__ float Bs[16][132];  // [k][n]
  const int m0 = blockIdx.y << 7;
  const int n0 = blockIdx.x << 7;
  const int t  = threadIdx.x;
  const int lr = t >> 2;            // 0..63  (row within tile for loads)
  const int lc = (t & 3) << 2;      // 0,4,8,12 (k within K-step)
  const int tr = t >> 4;            // 0..15
  const int tc = t & 15;            // 0..15

  float acc[8][8];
  #pragma unroll
  for (int i = 0; i < 8; ++i)
    #pragma unroll
    for (int j = 0; j < 8; ++j) acc[i][j] = 0.0f;

  const float* Ap = A  + (size_t)(m0 + lr) * lda + lc;
  const float* Bp = Bm + (size_t)(n0 + lr) * ldb + lc;
  const size_t a64 = (size_t)64 * lda;
  const size_t b64 = (size_t)64 * ldb;

  for (int k0 = 0; k0 < K; k0 += 16) {
    float4 a0 = *(const float4*)(Ap + k0);
    float4 a1 = *(const float4*)(Ap + a64 + k0);
    float4 c0 = *(const float4*)(Bp + k0);
    float4 c1 = *(const float4*)(Bp + b64 + k0);
    As[lc+0][lr] = a0.x; As[lc+1][lr] = a0.y; As[lc+2][lr] = a0.z; As[lc+3][lr] = a0.w;
    As[lc+0][lr+64] = a1.x; As[lc+1][lr+64] = a1.y; As[lc+2][lr+64] = a1.z; As[lc+3][lr+64] = a1.w;
    Bs[lc+0][lr] = c0.x; Bs[lc+1][lr] = c0.y; Bs[lc+2][lr] = c0.z; Bs[lc+3][lr] = c0.w;
    Bs[lc+0][lr+64] = c1.x; Bs[lc+1][lr+64] = c1.y; Bs[lc+2][lr+64] = c1.z; Bs[lc+3][lr+64] = c1.w;
    __syncthreads();
    #pragma unroll
    for (int kk = 0; kk < 16; ++kk) {
      float a[8], b[8];
      *(float4*)&a[0] = *(const float4*)&As[kk][tr*8];
      *(float4*)&a[4] = *(const float4*)&As[kk][tr*8+4];
      *(float4*)&b[0] = *(const float4*)&Bs[kk][tc*8];
      *(float4*)&b[4] = *(const float4*)&Bs[kk][tc*8+4];
      #pragma unroll
      for (int i = 0; i < 8; ++i)
        #pragma unroll
        for (int j = 0; j < 8; ++j)
          acc[i][j] = fmaf(a[i], b[j], acc[i][j]);
    }
    __syncthreads();
  }

  const float s = (EPI == 1) ? *sptr : 1.0f;
  #pragma unroll
  for (int i = 0; i < 8; ++i) {
    float* Cp = C + (size_t)(m0 + tr*8 + i) * ldc + n0 + tc*8;
    float v[8];
    #pragma unroll
    for (int j = 0; j < 8; ++j) {
      float x = acc[i][j];
      if (EPI == 1) x = lsq_sym(x, s);
      v[j] = x;
    }
    *(float4*)&Cp[0] = *(float4*)&v[0];
    *(float4*)&Cp[4] = *(float4*)&v[4];
  }
}

// quant (sym) + RoPE, in place. One thread owns the (d, d+64) pair -> no race.
// cos/sin: emb=concat([freqs,freqs]) => cos[d+64]==cos[d].
__global__ __launch_bounds__(256)
void quant_rope(float* __restrict__ qkv, int coloff, int nh,
                const float* __restrict__ cosp, const float* __restrict__ sinp,
                const float* __restrict__ sptr)
{
  const int i = blockIdx.x * 256 + threadIdx.x;   // over M_*nh*64, exact grid
  const int d = i & 63;
  const int h = (i >> 6) % nh;
  const int m = i / (nh << 6);
  const float s = *sptr;
  float* base = qkv + (size_t)m * LDQKV + coloff + h * HD_;
  float q1 = lsq_sym(base[d], s);
  float q2 = lsq_sym(base[d + 64], s);
  float c  = cosp[m * HD_ + d];
  float sn = sinp[m * HD_ + d];
  base[d]      = q1 * c - q2 * sn;   // x*cos + rot_half(x)*sin, rot[d] = -x[d+64]
  base[d + 64] = q2 * c + q1 * sn;   // rot[d+64] = x[d]
}

// quant (sym) only, for V, in place.
__global__ __launch_bounds__(256)
void quant_v(float* __restrict__ qkv, const float* __restrict__ sptr)
{
  const int i = blockIdx.x * 256 + threadIdx.x;   // M_*1024
  const int c = i & 1023;
  const int m = i >> 10;
  const float s = *sptr;
  float* p = qkv + (size_t)m * LDQKV + VOFF + c;
  *p = lsq_sym(*p, s);
}

// scores: logits[b,h,qi,ki] = lsq_asym(scale * q.k, s_attn) + mask  -> into d_out attn region
__global__ __launch_bounds__(256)
void scores_kernel(const float* __restrict__ qkv,
                   const float* __restrict__ mask,
                   float* __restrict__ attn,
                   const float* __restrict__ sptr)
{
  __shared__ float As[16][68];
  __shared__ float Bs[16][68];
  const int b = blockIdx.z, h = blockIdx.y;
  const int qi0 = (blockIdx.x >> 4) << 6;
  const int ki0 = (blockIdx.x & 15) << 6;
  const int t = threadIdx.x;
  const int lr = t >> 2, lc = (t & 3) << 2;
  const int tr = t >> 4, tc = t & 15;
  const float sa = *sptr;

  const float* Aq = qkv + (size_t)(b * S_ + qi0 + lr) * LDQKV + h * HD_ + lc;
  const float* Bk = qkv + (size_t)(b * S_ + ki0 + lr) * LDQKV + H_ + (h >> 2) * HD_ + lc;

  float acc[4][4];
  #pragma unroll
  for (int i = 0; i < 4; ++i)
    #pragma unroll
    for (int j = 0; j < 4; ++j) acc[i][j] = 0.0f;

  for (int k0 = 0; k0 < HD_; k0 += 16) {
    float4 a = *(const float4*)(Aq + k0);
    float4 c = *(const float4*)(Bk + k0);
    As[lc+0][lr] = a.x; As[lc+1][lr] = a.y; As[lc+2][lr] = a.z; As[lc+3][lr] = a.w;
    Bs[lc+0][lr] = c.x; Bs[lc+1][lr] = c.y; Bs[lc+2][lr] = c.z; Bs[lc+3][lr] = c.w;
    __syncthreads();
    #pragma unroll
    for (int kk = 0; kk < 16; ++kk) {
      float av[4], bv[4];
      *(float4*)av = *(const float4*)&As[kk][tr*4];
      *(float4*)bv = *(const float4*)&Bs[kk][tc*4];
      #pragma unroll
      for (int i = 0; i < 4; ++i)
        #pragma unroll
        for (int j = 0; j < 4; ++j)
          acc[i][j] = fmaf(av[i], bv[j], acc[i][j]);
    }
    __syncthreads();
  }

  #pragma unroll
  for (int i = 0; i < 4; ++i) {
    const int qi = qi0 + tr*4 + i;
    const float* mrow = mask + ((size_t)b * S_ + qi) * S_ + ki0 + tc*4;
    float* orow = attn + (((size_t)(b * NH_ + h)) * S_ + qi) * S_ + ki0 + tc*4;
    float v[4];
    #pragma unroll
    for (int j = 0; j < 4; ++j) {
      float x = acc[i][j] * SCALING;
      v[j] = lsq_asym(x, sa) + mrow[j];   // quant BEFORE mask add (ref order)
    }
    *(float4*)orow = *(float4*)v;
  }
}

// in-place row softmax over S=1024. masked logits ~ -3.4e38 -> expf==0 exactly.
__global__ __launch_bounds__(256)
void softmax_kernel(float* __restrict__ attn)
{
  float* p = attn + (size_t)blockIdx.x * S_;
  const int t = threadIdx.x;
  float4 x = ((float4*)p)[t];
  float m = fmaxf(fmaxf(x.x, x.y), fmaxf(x.z, x.w));
  #pragma unroll
  for (int off = 32; off; off >>= 1) m = fmaxf(m, __shfl_xor(m, off));
  __shared__ float red[8];
  const int wave = t >> 6, lane = t & 63;
  if (lane == 0) red[wave] = m;
  __syncthreads();
  m = fmaxf(fmaxf(red[0], red[1]), fmaxf(red[2], red[3]));
  float4 e;
  e.x = expf(x.x - m); e.y = expf(x.y - m); e.z = expf(x.z - m); e.w = expf(x.w - m);
  float sum = e.x + e.y + e.z + e.w;
  #pragma unroll
  for (int off = 32; off; off >>= 1) sum += __shfl_xor(sum, off);
  if (lane == 0) red[4 + wave] = sum;
  __syncthreads();
  const float tot = red[4] + red[5] + red[6] + red[7];
  e.x /= tot; e.y /= tot; e.z /= tot; e.w /= tot;
  ((float4*)p)[t] = e;
}

// PV: out[b,s,h,d] = lsq_asym(P @ V, s_after), written into the (dead) q columns of qkv
__global__ __launch_bounds__(256)
void pv_kernel(const float* __restrict__ attn,
               float* __restrict__ qkv,
               const float* __restrict__ sptr)
{
  __shared__ float As[16][68];   // [k][m] P tile
  __shared__ float Bs[16][68];   // [k][n] V tile
  const int b = blockIdx.z, h = blockIdx.y;
  const int qi0 = (blockIdx.x >> 1) << 6;
  const int n0  = (blockIdx.x & 1) << 6;
  const int t = threadIdx.x;
  const int lr = t >> 2, lc = (t & 3) << 2;
  const int tr = t >> 4, tc = t & 15;
  const float s = *sptr;

  const float* P = attn + ((size_t)(b * NH_ + h) * S_ + qi0 + lr) * S_ + lc;
  const float* V = qkv + (size_t)(b * S_ + (t >> 4)) * LDQKV + VOFF + (h >> 2) * HD_ + n0 + ((t & 15) << 2);

  float acc[4][4];
  #pragma unroll
  for (int i = 0; i < 4; ++i)
    #pragma unroll
    for (int j = 0; j < 4; ++j) acc[i][j] = 0.0f;

  for (int k0 = 0; k0 < S_; k0 += 16) {
    float4 a  = *(const float4*)(P + k0);
    float4 v4 = *(const float4*)(V + (size_t)k0 * LDQKV);
    As[lc+0][lr] = a.x; As[lc+1][lr] = a.y; As[lc+2][lr] = a.z; As[lc+3][lr] = a.w;
    *(float4*)&Bs[t >> 4][(t & 15) << 2] = v4;
    __syncthreads();
    #pragma unroll
    for (int kk = 0; kk < 16; ++kk) {
      float av[4], bv[4];
      *(float4*)av = *(const float4*)&As[kk][tr*4];
      *(float4*)bv = *(const float4*)&Bs[kk][tc*4];
      #pragma unroll
      for (int i = 0; i < 4; ++i)
        #pragma unroll
        for (int j = 0; j < 4; ++j)
          acc[i][j] = fmaf(av[i], bv[j], acc[i][j]);
    }
    __syncthreads();
  }

  #pragma unroll
  for (int i = 0; i < 4; ++i) {
    const int qi = qi0 + tr*4 + i;
    float* orow = qkv + (size_t)(b * S_ + qi) * LDQKV + h * HD_ + n0 + tc*4;
    float v[4];
    #pragma unroll
    for (int j = 0; j < 4; ++j) v[j] = lsq_asym(acc[i][j], s);
    *(float4*)orow = *(float4*)v;
  }
}

extern "C" void kernel_launch(void* const* d_in, const int* in_sizes, int n_in,
                              void* d_out, int out_size, void* d_ws, size_t ws_size,
                              hipStream_t stream)
{
  const float* hidden = (const float*)d_in[0];
  const float* cosp   = (const float*)d_in[1];
  const float* sinp   = (const float*)d_in[2];
  const float* mask   = (const float*)d_in[3];
  const float* Wq     = (const float*)d_in[4];
  const float* Wk     = (const float*)d_in[5];
  const float* Wv     = (const float*)d_in[6];
  const float* Wo     = (const float*)d_in[7];
  const float* s_q    = (const float*)d_in[8];
  const float* s_k    = (const float*)d_in[9];
  const float* s_v    = (const float*)d_in[10];
  const float* s_attn = (const float*)d_in[11];
  const float* s_after= (const float*)d_in[12];
  const float* s_o    = (const float*)d_in[13];

  float* out  = (float*)d_out;                 // (B,S,H) f32
  float* attn = out + (size_t)M_ * H_;         // (B,NH,S,S) f32 — also logits scratch
  float* qkv  = (float*)d_ws;                  // [M_][6144] f32, 100.7 MB

  dim3 blk(256, 1, 1);

  // 1) QKV projection (raw f32 into qkv)
  gemm_nt<0><<<dim3(H_/128,  M_/128), blk, 0, stream>>>(hidden, H_, Wq, H_, qkv,              LDQKV, H_, nullptr);
  gemm_nt<0><<<dim3(1024/128,M_/128), blk, 0, stream>>>(hidden, H_, Wk, H_, qkv + H_,         LDQKV, H_, nullptr);
  gemm_nt<0><<<dim3(1024/128,M_/128), blk, 0, stream>>>(hidden, H_, Wv, H_, qkv + VOFF,       LDQKV, H_, nullptr);

  // 2) quantize + RoPE (q,k), quantize (v) — in place
  quant_rope<<<dim3(M_*NH_*64/256),  blk, 0, stream>>>(qkv, 0,  NH_,  cosp, sinp, s_q);
  quant_rope<<<dim3(M_*NKV_*64/256), blk, 0, stream>>>(qkv, H_, NKV_, cosp, sinp, s_k);
  quant_v   <<<dim3(M_*1024/256),    blk, 0, stream>>>(qkv, s_v);

  // 3) scores -> quant -> +mask (logits into d_out attn region), then softmax in place
  scores_kernel <<<dim3(256, NH_, B_), blk, 0, stream>>>(qkv, mask, attn, s_attn);
  softmax_kernel<<<dim3(B_*NH_*S_),    blk, 0, stream>>>(attn);

  // 4) PV + quant, into dead q columns of qkv (layout = (b,s,h*HD+d) for final GEMM)
  pv_kernel<<<dim3(32, NH_, B_), blk, 0, stream>>>(attn, qkv, s_after);

  // 5) out projection + sym quant into d_out
  gemm_nt<1><<<dim3(H_/128, M_/128), blk, 0, stream>>>(qkv, LDQKV, Wo, H_, out, H_, H_, s_o);
}

// Round 4
// 2547.337 us; speedup vs baseline: 2.1532x; 2.1532x over previous
//
#include <hip/hip_runtime.h>
#include <math.h>

// Problem constants (B,S,H)=(4,1024,4096), NH=32, NKV=8, HD=128, LEVEL=256
#define B_   4
#define S_   1024
#define H_   4096
#define NH_  32
#define NKV_ 8
#define HD_  128
#define M_   (B_*S_)          // 4096 rows (b*S+s)
#define LDQKV 6144            // qkv ws row: [q 4096 | k 1024 | v 1024]
#define VOFF (H_ + NKV_*HD_)  // 5120
#define SCALING 0.08838834764831845f  // HD**-0.5

typedef _Float16 f16;
typedef __attribute__((ext_vector_type(4))) _Float16 f16x4;
typedef __attribute__((ext_vector_type(8))) _Float16 f16x8;
typedef __attribute__((ext_vector_type(4))) float f32x4;

// lsq_quant forward: round(clip(x/s,qn,qp))*s ; rintf = round-half-even (matches jnp.round)
__device__ __forceinline__ float lsq_sym(float x, float s) {
  float xs = x / s;
  xs = fminf(fmaxf(xs, -128.0f), 127.0f);
  return rintf(xs) * s;
}
__device__ __forceinline__ float lsq_asym(float x, float s) {
  float xs = x / s;
  xs = fminf(fmaxf(xs, 0.0f), 255.0f);
  return rintf(xs) * s;
}

struct f16pair { f16 hi, lo; };
__device__ __forceinline__ f16pair cvt_hilo(float x) {
  f16pair r;
  r.hi = (f16)x;
  r.lo = (f16)(x - (float)r.hi);   // x-hi exact (Sterbenz); lo err <= 2^-22 |x|
  return r;
}

// ---------------------------------------------------------------------------
// Split-f16 MFMA GEMM:  C[M,N] = A[M,K] * B[N,K]^T  (both K-major, "NT")
// 128x128 tile, 256 thr (4 waves, 2x2 of 64x64), BK=32, mfma 16x16x32_f16.
// A*B = Ahi*Bhi + Ahi*Blo + Alo*Bhi  (lo*lo dropped, ~2^-22 rel)
// EPI: 0 = raw f32 store, 1 = lsq_sym(s) epilogue.
// ---------------------------------------------------------------------------
#define LDT 40   // padded leading dim in f16 units (80B rows -> uniform 2-way banks)

template<int EPI>
__global__ __launch_bounds__(256)
void gemm_f16split(const float* __restrict__ A, int lda,
                   const float* __restrict__ Bm, int ldb,
                   float* __restrict__ C, int ldc, int K,
                   const float* __restrict__ sptr)
{
  __shared__ f16 sAhi[128*LDT];
  __shared__ f16 sAlo[128*LDT];
  __shared__ f16 sBhi[128*LDT];
  __shared__ f16 sBlo[128*LDT];

  const int m0 = blockIdx.y << 7;
  const int n0 = blockIdx.x << 7;
  const int t    = threadIdx.x;
  const int lane = t & 63;
  const int wave = t >> 6;
  const int wm = (wave & 1) << 6;       // 0 or 64
  const int wn = (wave >> 1) << 6;      // 0 or 64
  const int lrow = lane & 15;
  const int kg   = (lane >> 4) << 3;    // 0,8,16,24

  const int srow = t >> 3;              // 0..31
  const int scol = (t & 7) << 2;        // 0..28

  f32x4 acc[4][4];
  #pragma unroll
  for (int i = 0; i < 4; ++i)
    #pragma unroll
    for (int j = 0; j < 4; ++j) acc[i][j] = (f32x4){0.f,0.f,0.f,0.f};

  for (int k0 = 0; k0 < K; k0 += 32) {
    // ---- stage: load f32, convert to (hi,lo) f16, write padded LDS ----
    #pragma unroll
    for (int it = 0; it < 4; ++it) {
      const int row = srow + (it << 5);           // 0..127
      float4 av = *(const float4*)(A  + (size_t)(m0 + row) * lda + k0 + scol);
      float4 bv = *(const float4*)(Bm + (size_t)(n0 + row) * ldb + k0 + scol);
      f16x4 ah, al, bh, bl;
      f16pair p;
      p = cvt_hilo(av.x); ah.x = p.hi; al.x = p.lo;
      p = cvt_hilo(av.y); ah.y = p.hi; al.y = p.lo;
      p = cvt_hilo(av.z); ah.z = p.hi; al.z = p.lo;
      p = cvt_hilo(av.w); ah.w = p.hi; al.w = p.lo;
      p = cvt_hilo(bv.x); bh.x = p.hi; bl.x = p.lo;
      p = cvt_hilo(bv.y); bh.y = p.hi; bl.y = p.lo;
      p = cvt_hilo(bv.z); bh.z = p.hi; bl.z = p.lo;
      p = cvt_hilo(bv.w); bh.w = p.hi; bl.w = p.lo;
      const int o = row * LDT + scol;
      *(f16x4*)&sAhi[o] = ah;  *(f16x4*)&sAlo[o] = al;
      *(f16x4*)&sBhi[o] = bh;  *(f16x4*)&sBlo[o] = bl;
    }
    __syncthreads();

    // ---- fragments: lane l -> row (l&15), k = (l>>4)*8 + 0..7 ----
    f16x8 ahi[4], alo[4], bhi[4], blo[4];
    #pragma unroll
    for (int i = 0; i < 4; ++i) {
      const int ar = (wm + (i << 4) + lrow) * LDT + kg;
      ahi[i] = *(const f16x8*)&sAhi[ar];
      alo[i] = *(const f16x8*)&sAlo[ar];
      const int br = (wn + (i << 4) + lrow) * LDT + kg;
      bhi[i] = *(const f16x8*)&sBhi[br];
      blo[i] = *(const f16x8*)&sBlo[br];
    }
    #pragma unroll
    for (int i = 0; i < 4; ++i)
      #pragma unroll
      for (int j = 0; j < 4; ++j) {
        acc[i][j] = __builtin_amdgcn_mfma_f32_16x16x32_f16(ahi[i], bhi[j], acc[i][j], 0, 0, 0);
        acc[i][j] = __builtin_amdgcn_mfma_f32_16x16x32_f16(alo[i], bhi[j], acc[i][j], 0, 0, 0);
        acc[i][j] = __builtin_amdgcn_mfma_f32_16x16x32_f16(ahi[i], blo[j], acc[i][j], 0, 0, 0);
      }
    __syncthreads();
  }

  // ---- epilogue: C/D layout col=lane&15, row=(lane>>4)*4+r ----
  const float s = (EPI == 1) ? *sptr : 1.0f;
  #pragma unroll
  for (int i = 0; i < 4; ++i)
    #pragma unroll
    for (int j = 0; j < 4; ++j) {
      const int gr = m0 + wm + (i << 4) + ((lane >> 4) << 2);
      const int gc = n0 + wn + (j << 4) + (lane & 15);
      float* Cp = C + (size_t)gr * ldc + gc;
      #pragma unroll
      for (int r = 0; r < 4; ++r) {
        float x = acc[i][j][r];
        if (EPI == 1) x = lsq_sym(x, s);
        Cp[(size_t)r * ldc] = x;
      }
    }
}

// quant (sym) + RoPE, in place. One thread owns the (d, d+64) pair -> no race.
__global__ __launch_bounds__(256)
void quant_rope(float* __restrict__ qkv, int coloff, int nh,
                const float* __restrict__ cosp, const float* __restrict__ sinp,
                const float* __restrict__ sptr)
{
  const int i = blockIdx.x * 256 + threadIdx.x;
  const int d = i & 63;
  const int h = (i >> 6) % nh;
  const int m = i / (nh << 6);
  const float s = *sptr;
  float* base = qkv + (size_t)m * LDQKV + coloff + h * HD_;
  float q1 = lsq_sym(base[d], s);
  float q2 = lsq_sym(base[d + 64], s);
  float c  = cosp[m * HD_ + d];
  float sn = sinp[m * HD_ + d];
  base[d]      = q1 * c - q2 * sn;
  base[d + 64] = q2 * c + q1 * sn;
}

__global__ __launch_bounds__(256)
void quant_v(float* __restrict__ qkv, const float* __restrict__ sptr)
{
  const int i = blockIdx.x * 256 + threadIdx.x;
  const int c = i & 1023;
  const int m = i >> 10;
  const float s = *sptr;
  float* p = qkv + (size_t)m * LDQKV + VOFF + c;
  *p = lsq_sym(*p, s);
}

// scores: logits = lsq_asym(scale * q.k, s_attn) + mask -> d_out attn region
__global__ __launch_bounds__(256)
void scores_kernel(const float* __restrict__ qkv,
                   const float* __restrict__ mask,
                   float* __restrict__ attn,
                   const float* __restrict__ sptr)
{
  __shared__ float As[16][68];
  __shared__ float Bs[16][68];
  const int b = blockIdx.z, h = blockIdx.y;
  const int qi0 = (blockIdx.x >> 4) << 6;
  const int ki0 = (blockIdx.x & 15) << 6;
  const int t = threadIdx.x;
  const int lr = t >> 2, lc = (t & 3) << 2;
  const int tr = t >> 4, tc = t & 15;
  const float sa = *sptr;

  const float* Aq = qkv + (size_t)(b * S_ + qi0 + lr) * LDQKV + h * HD_ + lc;
  const float* Bk = qkv + (size_t)(b * S_ + ki0 + lr) * LDQKV + H_ + (h >> 2) * HD_ + lc;

  float acc[4][4];
  #pragma unroll
  for (int i = 0; i < 4; ++i)
    #pragma unroll
    for (int j = 0; j < 4; ++j) acc[i][j] = 0.0f;

  for (int k0 = 0; k0 < HD_; k0 += 16) {
    float4 a = *(const float4*)(Aq + k0);
    float4 c = *(const float4*)(Bk + k0);
    As[lc+0][lr] = a.x; As[lc+1][lr] = a.y; As[lc+2][lr] = a.z; As[lc+3][lr] = a.w;
    Bs[lc+0][lr] = c.x; Bs[lc+1][lr] = c.y; Bs[lc+2][lr] = c.z; Bs[lc+3][lr] = c.w;
    __syncthreads();
    #pragma unroll
    for (int kk = 0; kk < 16; ++kk) {
      float av[4], bv[4];
      *(float4*)av = *(const float4*)&As[kk][tr*4];
      *(float4*)bv = *(const float4*)&Bs[kk][tc*4];
      #pragma unroll
      for (int i = 0; i < 4; ++i)
        #pragma unroll
        for (int j = 0; j < 4; ++j)
          acc[i][j] = fmaf(av[i], bv[j], acc[i][j]);
    }
    __syncthreads();
  }

  #pragma unroll
  for (int i = 0; i < 4; ++i) {
    const int qi = qi0 + tr*4 + i;
    const float* mrow = mask + ((size_t)b * S_ + qi) * S_ + ki0 + tc*4;
    float* orow = attn + (((size_t)(b * NH_ + h)) * S_ + qi) * S_ + ki0 + tc*4;
    float v[4];
    #pragma unroll
    for (int j = 0; j < 4; ++j) {
      float x = acc[i][j] * SCALING;
      v[j] = lsq_asym(x, sa) + mrow[j];
    }
    *(float4*)orow = *(float4*)v;
  }
}

// in-place row softmax over S=1024
__global__ __launch_bounds__(256)
void softmax_kernel(float* __restrict__ attn)
{
  float* p = attn + (size_t)blockIdx.x * S_;
  const int t = threadIdx.x;
  float4 x = ((float4*)p)[t];
  float m = fmaxf(fmaxf(x.x, x.y), fmaxf(x.z, x.w));
  #pragma unroll
  for (int off = 32; off; off >>= 1) m = fmaxf(m, __shfl_xor(m, off));
  __shared__ float red[8];
  const int wave = t >> 6, lane = t & 63;
  if (lane == 0) red[wave] = m;
  __syncthreads();
  m = fmaxf(fmaxf(red[0], red[1]), fmaxf(red[2], red[3]));
  float4 e;
  e.x = expf(x.x - m); e.y = expf(x.y - m); e.z = expf(x.z - m); e.w = expf(x.w - m);
  float sum = e.x + e.y + e.z + e.w;
  #pragma unroll
  for (int off = 32; off; off >>= 1) sum += __shfl_xor(sum, off);
  if (lane == 0) red[4 + wave] = sum;
  __syncthreads();
  const float tot = red[4] + red[5] + red[6] + red[7];
  e.x /= tot; e.y /= tot; e.z /= tot; e.w /= tot;
  ((float4*)p)[t] = e;
}

// PV: out = lsq_asym(P @ V, s_after) into dead q columns of qkv
__global__ __launch_bounds__(256)
void pv_kernel(const float* __restrict__ attn,
               float* __restrict__ qkv,
               const float* __restrict__ sptr)
{
  __shared__ float As[16][68];
  __shared__ float Bs[16][68];
  const int b = blockIdx.z, h = blockIdx.y;
  const int qi0 = (blockIdx.x >> 1) << 6;
  const int n0  = (blockIdx.x & 1) << 6;
  const int t = threadIdx.x;
  const int lr = t >> 2, lc = (t & 3) << 2;
  const int tr = t >> 4, tc = t & 15;
  const float s = *sptr;

  const float* P = attn + ((size_t)(b * NH_ + h) * S_ + qi0 + lr) * S_ + lc;
  const float* V = qkv + (size_t)(b * S_ + (t >> 4)) * LDQKV + VOFF + (h >> 2) * HD_ + n0 + ((t & 15) << 2);

  float acc[4][4];
  #pragma unroll
  for (int i = 0; i < 4; ++i)
    #pragma unroll
    for (int j = 0; j < 4; ++j) acc[i][j] = 0.0f;

  for (int k0 = 0; k0 < S_; k0 += 16) {
    float4 a  = *(const float4*)(P + k0);
    float4 v4 = *(const float4*)(V + (size_t)k0 * LDQKV);
    As[lc+0][lr] = a.x; As[lc+1][lr] = a.y; As[lc+2][lr] = a.z; As[lc+3][lr] = a.w;
    *(float4*)&Bs[t >> 4][(t & 15) << 2] = v4;
    __syncthreads();
    #pragma unroll
    for (int kk = 0; kk < 16; ++kk) {
      float av[4], bv[4];
      *(float4*)av = *(const float4*)&As[kk][tr*4];
      *(float4*)bv = *(const float4*)&Bs[kk][tc*4];
      #pragma unroll
      for (int i = 0; i < 4; ++i)
        #pragma unroll
        for (int j = 0; j < 4; ++j)
          acc[i][j] = fmaf(av[i], bv[j], acc[i][j]);
    }
    __syncthreads();
  }

  #pragma unroll
  for (int i = 0; i < 4; ++i) {
    const int qi = qi0 + tr*4 + i;
    float* orow = qkv + (size_t)(b * S_ + qi) * LDQKV + h * HD_ + n0 + tc*4;
    float v[4];
    #pragma unroll
    for (int j = 0; j < 4; ++j) v[j] = lsq_asym(acc[i][j], s);
    *(float4*)orow = *(float4*)v;
  }
}

extern "C" void kernel_launch(void* const* d_in, const int* in_sizes, int n_in,
                              void* d_out, int out_size, void* d_ws, size_t ws_size,
                              hipStream_t stream)
{
  const float* hidden = (const float*)d_in[0];
  const float* cosp   = (const float*)d_in[1];
  const float* sinp   = (const float*)d_in[2];
  const float* mask   = (const float*)d_in[3];
  const float* Wq     = (const float*)d_in[4];
  const float* Wk     = (const float*)d_in[5];
  const float* Wv     = (const float*)d_in[6];
  const float* Wo     = (const float*)d_in[7];
  const float* s_q    = (const float*)d_in[8];
  const float* s_k    = (const float*)d_in[9];
  const float* s_v    = (const float*)d_in[10];
  const float* s_attn = (const float*)d_in[11];
  const float* s_after= (const float*)d_in[12];
  const float* s_o    = (const float*)d_in[13];

  float* out  = (float*)d_out;                 // (B,S,H) f32
  float* attn = out + (size_t)M_ * H_;         // (B,NH,S,S) f32 — logits scratch, then final
  float* qkv  = (float*)d_ws;                  // [M_][6144] f32, 100.7 MB

  dim3 blk(256, 1, 1);

  // 1) QKV projection (split-f16 MFMA, raw f32 out into qkv)
  gemm_f16split<0><<<dim3(H_/128,   M_/128), blk, 0, stream>>>(hidden, H_, Wq, H_, qkv,        LDQKV, H_, nullptr);
  gemm_f16split<0><<<dim3(1024/128, M_/128), blk, 0, stream>>>(hidden, H_, Wk, H_, qkv + H_,   LDQKV, H_, nullptr);
  gemm_f16split<0><<<dim3(1024/128, M_/128), blk, 0, stream>>>(hidden, H_, Wv, H_, qkv + VOFF, LDQKV, H_, nullptr);

  // 2) quantize + RoPE (q,k), quantize (v) — in place
  quant_rope<<<dim3(M_*NH_*64/256),  blk, 0, stream>>>(qkv, 0,  NH_,  cosp, sinp, s_q);
  quant_rope<<<dim3(M_*NKV_*64/256), blk, 0, stream>>>(qkv, H_, NKV_, cosp, sinp, s_k);
  quant_v   <<<dim3(M_*1024/256),    blk, 0, stream>>>(qkv, s_v);

  // 3) scores -> quant -> +mask -> softmax (in d_out attn region)
  scores_kernel <<<dim3(256, NH_, B_), blk, 0, stream>>>(qkv, mask, attn, s_attn);
  softmax_kernel<<<dim3(B_*NH_*S_),    blk, 0, stream>>>(attn);

  // 4) PV + quant, into dead q columns of qkv
  pv_kernel<<<dim3(32, NH_, B_), blk, 0, stream>>>(attn, qkv, s_after);

  // 5) out projection + sym quant into d_out (split-f16 MFMA)
  gemm_f16split<1><<<dim3(H_/128, M_/128), blk, 0, stream>>>(qkv, LDQKV, Wo, H_, out, H_, H_, s_o);
}

// Round 6
// 2326.674 us; speedup vs baseline: 2.3574x; 1.0948x over previous
//
#include <hip/hip_runtime.h>
#include <math.h>

// Problem constants (B,S,H)=(4,1024,4096), NH=32, NKV=8, HD=128, LEVEL=256
#define B_   4
#define S_   1024
#define H_   4096
#define NH_  32
#define NKV_ 8
#define HD_  128
#define M_   (B_*S_)          // 4096 rows (b*S+s)
#define LDQKV 6144            // qkv ws row (f32): [q 4096 | k 1024 | v 1024]
#define VOFF (H_ + NKV_*HD_)  // 5120
#define LDF16 (2*LDQKV)       // 12288 f16 per qkv row
#define SCALING 0.08838834764831845f  // HD**-0.5

typedef _Float16 f16;
typedef __attribute__((ext_vector_type(4))) _Float16 f16x4;
typedef __attribute__((ext_vector_type(8))) _Float16 f16x8;
typedef __attribute__((ext_vector_type(4))) float f32x4;

// lsq_quant forward: round(clip(x/s,qn,qp))*s ; rintf = round-half-even (matches jnp.round)
__device__ __forceinline__ float lsq_sym(float x, float s) {
  float xs = x / s;
  xs = fminf(fmaxf(xs, -128.0f), 127.0f);
  return rintf(xs) * s;
}
__device__ __forceinline__ float lsq_asym(float x, float s) {
  float xs = x / s;
  xs = fminf(fmaxf(xs, 0.0f), 255.0f);
  return rintf(xs) * s;
}

struct f16pair { f16 hi, lo; };
__device__ __forceinline__ f16pair cvt_hilo(float x) {
  f16pair r;
  r.hi = (f16)x;
  r.lo = (f16)(x - (float)r.hi);   // x-hi exact (Sterbenz); hi+lo = x + O(2^-22|x|)
  return r;
}

// async global->LDS, 16B per lane; LDS dest wave-uniform base + lane*16
__device__ __forceinline__ void gload16(const void* g, void* l) {
  __builtin_amdgcn_global_load_lds((const __attribute__((address_space(1))) void*)g,
                                   (__attribute__((address_space(3))) void*)l, 16, 0, 0);
}

// ---------------------------------------------------------------------------
// split kernels: f32 -> (hi,lo) f16
// ---------------------------------------------------------------------------
__global__ __launch_bounds__(256)
void split_flat(const float* __restrict__ src, f16* __restrict__ hi, f16* __restrict__ lo)
{
  const size_t i = ((size_t)blockIdx.x * 256 + threadIdx.x) * 4;
  float4 v = *(const float4*)(src + i);
  f16x4 h, l; f16pair p;
  p = cvt_hilo(v.x); h.x = p.hi; l.x = p.lo;
  p = cvt_hilo(v.y); h.y = p.hi; l.y = p.lo;
  p = cvt_hilo(v.z); h.z = p.hi; l.z = p.lo;
  p = cvt_hilo(v.w); h.w = p.hi; l.w = p.lo;
  *(f16x4*)(hi + i) = h;
  *(f16x4*)(lo + i) = l;
}

// Wo split into the (dead) f16 view of qkv rows: hi at col 4096, lo at col 8192
__global__ __launch_bounds__(256)
void split_wo(const float* __restrict__ Wo, f16* __restrict__ base)
{
  const size_t i = ((size_t)blockIdx.x * 256 + threadIdx.x) * 4;
  const int n = (int)(i >> 12);        // row (4096 cols per row)
  const int k = (int)(i & 4095);
  float4 v = *(const float4*)(Wo + i);
  f16x4 h, l; f16pair p;
  p = cvt_hilo(v.x); h.x = p.hi; l.x = p.lo;
  p = cvt_hilo(v.y); h.y = p.hi; l.y = p.lo;
  p = cvt_hilo(v.z); h.z = p.hi; l.z = p.lo;
  p = cvt_hilo(v.w); h.w = p.hi; l.w = p.lo;
  f16* rp = base + (size_t)n * LDF16;
  *(f16x4*)(rp + 4096 + k) = h;
  *(f16x4*)(rp + 8192 + k) = l;
}

// ---------------------------------------------------------------------------
// MFMA GEMM, pre-split f16 operands:  C[M,N] = A[M,K] * B[N,K]^T
// 256x128 block tile, 4 waves (2Mx2N), wave tile 128x64, BK=32.
// ATERMS=2: A has hi+lo -> Ahi*Bhi + Ahi*Blo + Alo*Bhi  (3-term, ~f32 acc)
// ATERMS=1: A exact f16  -> A*Bhi + A*Blo               (2-term, ~f32 acc)
// Staging: global_load_lds w16, linear LDS [rows][32] f16 with XOR k-chunk
// swizzle (pre-swizzled global source; swizzled ds_read).
// EPI 0: raw f32 store. EPI 1: x = acc * (*sA), store lsq_sym(x, *sQ).
// ---------------------------------------------------------------------------
template<int ATERMS, int EPI>
__global__ __launch_bounds__(256, 2)
void gemm_mfma(const f16* __restrict__ Ahi, const f16* __restrict__ Alo, int lda,
               const f16* __restrict__ Bhi, const f16* __restrict__ Blo, int ldb,
               float* __restrict__ C, int ldc, int K,
               const float* __restrict__ sA, const float* __restrict__ sQ)
{
  __shared__ f16 sAh[256 * 32];
  __shared__ f16 sAl[(ATERMS == 2) ? 256 * 32 : 64];
  __shared__ f16 sBh[128 * 32];
  __shared__ f16 sBl[128 * 32];

  const int m0 = blockIdx.y << 8;
  const int n0 = blockIdx.x << 7;
  const int t    = threadIdx.x;
  const int lane = t & 63;
  const int wv   = t >> 6;
  const int wm   = (wv >> 1) << 7;   // 0 or 128
  const int wn   = (wv & 1) << 6;    // 0 or 64
  const int lrow = lane & 15;
  const int kg   = (lane >> 4) << 3; // 0,8,16,24 (f16 k-offset)
  const int fsw  = (lrow & 3) << 3;  // frag-read XOR swizzle

  // staging lane mapping: 16 rows per 1KB instr; lane -> row sr, k-chunk slot
  const int sr   = lane >> 2;        // 0..15
  const int slot = lane & 3;
  const int kcs  = ((slot ^ (sr & 3)) << 3);  // pre-swizzled global k offset

  f32x4 acc[8][4];
  #pragma unroll
  for (int i = 0; i < 8; ++i)
    #pragma unroll
    for (int j = 0; j < 4; ++j) acc[i][j] = (f32x4){0.f, 0.f, 0.f, 0.f};

  for (int k0 = 0; k0 < K; k0 += 32) {
    // ---- stage A: 256 rows, wave w owns rows [w*64, w*64+64) ----
    #pragma unroll
    for (int i = 0; i < 4; ++i) {
      const int rowb = (wv << 6) + (i << 4);
      const size_t goff = (size_t)(m0 + rowb + sr) * lda + k0 + kcs;
      gload16(Ahi + goff, &sAh[rowb * 32]);
      if constexpr (ATERMS == 2) gload16(Alo + goff, &sAl[rowb * 32]);
    }
    // ---- stage B: 128 rows, wave w owns rows [w*32, w*32+32) ----
    #pragma unroll
    for (int i = 0; i < 2; ++i) {
      const int rowb = (wv << 5) + (i << 4);
      const size_t goff = (size_t)(n0 + rowb + sr) * ldb + k0 + kcs;
      gload16(Bhi + goff, &sBh[rowb * 32]);
      gload16(Blo + goff, &sBl[rowb * 32]);
    }
    __syncthreads();   // drains vmcnt (global_load_lds) before reads

    f16x8 a[8], bh[4], bl[4];
    #pragma unroll
    for (int j = 0; j < 4; ++j) {
      const int r = wn + (j << 4) + lrow;
      bh[j] = *(const f16x8*)&sBh[r * 32 + (kg ^ fsw)];
      bl[j] = *(const f16x8*)&sBl[r * 32 + (kg ^ fsw)];
    }
    #pragma unroll
    for (int i = 0; i < 8; ++i)
      a[i] = *(const f16x8*)&sAh[(wm + (i << 4) + lrow) * 32 + (kg ^ fsw)];
    #pragma unroll
    for (int i = 0; i < 8; ++i)
      #pragma unroll
      for (int j = 0; j < 4; ++j) {
        acc[i][j] = __builtin_amdgcn_mfma_f32_16x16x32_f16(a[i], bh[j], acc[i][j], 0, 0, 0);
        acc[i][j] = __builtin_amdgcn_mfma_f32_16x16x32_f16(a[i], bl[j], acc[i][j], 0, 0, 0);
      }
    if constexpr (ATERMS == 2) {
      #pragma unroll
      for (int i = 0; i < 8; ++i)
        a[i] = *(const f16x8*)&sAl[(wm + (i << 4) + lrow) * 32 + (kg ^ fsw)];
      #pragma unroll
      for (int i = 0; i < 8; ++i)
        #pragma unroll
        for (int j = 0; j < 4; ++j)
          acc[i][j] = __builtin_amdgcn_mfma_f32_16x16x32_f16(a[i], bh[j], acc[i][j], 0, 0, 0);
    }
    __syncthreads();   // protect LDS before next-iter staging
  }

  // ---- epilogue: C/D layout col=lane&15, row=(lane>>4)*4+r ----
  float sAv = 1.0f, sQv = 1.0f;
  if constexpr (EPI == 1) { sAv = *sA; sQv = *sQ; }
  #pragma unroll
  for (int i = 0; i < 8; ++i)
    #pragma unroll
    for (int j = 0; j < 4; ++j) {
      const int gr = m0 + wm + (i << 4) + ((lane >> 4) << 2);
      const int gc = n0 + wn + (j << 4) + (lane & 15);
      float* Cp = C + (size_t)gr * ldc + gc;
      #pragma unroll
      for (int r = 0; r < 4; ++r) {
        float x = acc[i][j][r];
        if constexpr (EPI == 1) x = lsq_sym(x * sAv, sQv);
        Cp[(size_t)r * ldc] = x;
      }
    }
}

// quant (sym) + RoPE, in place (f32 qkv cols). One thread owns (d, d+64) pair.
__global__ __launch_bounds__(256)
void quant_rope(float* __restrict__ qkv, int coloff, int nh,
                const float* __restrict__ cosp, const float* __restrict__ sinp,
                const float* __restrict__ sptr)
{
  const int i = blockIdx.x * 256 + threadIdx.x;
  const int d = i & 63;
  const int h = (i >> 6) % nh;
  const int m = i / (nh << 6);
  const float s = *sptr;
  float* base = qkv + (size_t)m * LDQKV + coloff + h * HD_;
  float q1 = lsq_sym(base[d], s);
  float q2 = lsq_sym(base[d + 64], s);
  float c  = cosp[m * HD_ + d];
  float sn = sinp[m * HD_ + d];
  base[d]      = q1 * c - q2 * sn;
  base[d + 64] = q2 * c + q1 * sn;
}

__global__ __launch_bounds__(256)
void quant_v(float* __restrict__ qkv, const float* __restrict__ sptr)
{
  const int i = blockIdx.x * 256 + threadIdx.x;
  const int c = i & 1023;
  const int m = i >> 10;
  const float s = *sptr;
  float* p = qkv + (size_t)m * LDQKV + VOFF + c;
  *p = lsq_sym(*p, s);
}

// scores: logits = lsq_asym(scale * q.k, s_attn) + mask -> d_out attn region
__global__ __launch_bounds__(256)
void scores_kernel(const float* __restrict__ qkv,
                   const float* __restrict__ mask,
                   float* __restrict__ attn,
                   const float* __restrict__ sptr)
{
  __shared__ float As[16][68];
  __shared__ float Bs[16][68];
  const int b = blockIdx.z, h = blockIdx.y;
  const int qi0 = (blockIdx.x >> 4) << 6;
  const int ki0 = (blockIdx.x & 15) << 6;
  const int t = threadIdx.x;
  const int lr = t >> 2, lc = (t & 3) << 2;
  const int tr = t >> 4, tc = t & 15;
  const float sa = *sptr;

  const float* Aq = qkv + (size_t)(b * S_ + qi0 + lr) * LDQKV + h * HD_ + lc;
  const float* Bk = qkv + (size_t)(b * S_ + ki0 + lr) * LDQKV + H_ + (h >> 2) * HD_ + lc;

  float acc[4][4];
  #pragma unroll
  for (int i = 0; i < 4; ++i)
    #pragma unroll
    for (int j = 0; j < 4; ++j) acc[i][j] = 0.0f;

  for (int k0 = 0; k0 < HD_; k0 += 16) {
    float4 a = *(const float4*)(Aq + k0);
    float4 c = *(const float4*)(Bk + k0);
    As[lc+0][lr] = a.x; As[lc+1][lr] = a.y; As[lc+2][lr] = a.z; As[lc+3][lr] = a.w;
    Bs[lc+0][lr] = c.x; Bs[lc+1][lr] = c.y; Bs[lc+2][lr] = c.z; Bs[lc+3][lr] = c.w;
    __syncthreads();
    #pragma unroll
    for (int kk = 0; kk < 16; ++kk) {
      float av[4], bv[4];
      *(float4*)av = *(const float4*)&As[kk][tr*4];
      *(float4*)bv = *(const float4*)&Bs[kk][tc*4];
      #pragma unroll
      for (int i = 0; i < 4; ++i)
        #pragma unroll
        for (int j = 0; j < 4; ++j)
          acc[i][j] = fmaf(av[i], bv[j], acc[i][j]);
    }
    __syncthreads();
  }

  #pragma unroll
  for (int i = 0; i < 4; ++i) {
    const int qi = qi0 + tr*4 + i;
    const float* mrow = mask + ((size_t)b * S_ + qi) * S_ + ki0 + tc*4;
    float* orow = attn + (((size_t)(b * NH_ + h)) * S_ + qi) * S_ + ki0 + tc*4;
    float v[4];
    #pragma unroll
    for (int j = 0; j < 4; ++j) {
      float x = acc[i][j] * SCALING;
      v[j] = lsq_asym(x, sa) + mrow[j];
    }
    *(float4*)orow = *(float4*)v;
  }
}

// in-place row softmax over S=1024
__global__ __launch_bounds__(256)
void softmax_kernel(float* __restrict__ attn)
{
  float* p = attn + (size_t)blockIdx.x * S_;
  const int t = threadIdx.x;
  float4 x = ((float4*)p)[t];
  float m = fmaxf(fmaxf(x.x, x.y), fmaxf(x.z, x.w));
  #pragma unroll
  for (int off = 32; off; off >>= 1) m = fmaxf(m, __shfl_xor(m, off));
  __shared__ float red[8];
  const int wave = t >> 6, lane = t & 63;
  if (lane == 0) red[wave] = m;
  __syncthreads();
  m = fmaxf(fmaxf(red[0], red[1]), fmaxf(red[2], red[3]));
  float4 e;
  e.x = expf(x.x - m); e.y = expf(x.y - m); e.z = expf(x.z - m); e.w = expf(x.w - m);
  float sum = e.x + e.y + e.z + e.w;
  #pragma unroll
  for (int off = 32; off; off >>= 1) sum += __shfl_xor(sum, off);
  if (lane == 0) red[4 + wave] = sum;
  __syncthreads();
  const float tot = red[4] + red[5] + red[6] + red[7];
  e.x /= tot; e.y /= tot; e.z /= tot; e.w /= tot;
  ((float4*)p)[t] = e;
}

// PV: int = round(clip((P@V)/s_after, 0, 255)) stored as EXACT f16 integer
// into the f16 view of qkv, cols [0,4096)  (q f32 cols are dead after scores)
__global__ __launch_bounds__(256)
void pv_kernel(const float* __restrict__ attn,
               float* __restrict__ qkv,
               const float* __restrict__ sptr)
{
  __shared__ float As[16][68];
  __shared__ float Bs[16][68];
  const int b = blockIdx.z, h = blockIdx.y;
  const int qi0 = (blockIdx.x >> 1) << 6;
  const int n0  = (blockIdx.x & 1) << 6;
  const int t = threadIdx.x;
  const int lr = t >> 2, lc = (t & 3) << 2;
  const int tr = t >> 4, tc = t & 15;
  const float s = *sptr;

  const float* P = attn + ((size_t)(b * NH_ + h) * S_ + qi0 + lr) * S_ + lc;
  const float* V = qkv + (size_t)(b * S_ + (t >> 4)) * LDQKV + VOFF + (h >> 2) * HD_ + n0 + ((t & 15) << 2);

  float acc[4][4];
  #pragma unroll
  for (int i = 0; i < 4; ++i)
    #pragma unroll
    for (int j = 0; j < 4; ++j) acc[i][j] = 0.0f;

  for (int k0 = 0; k0 < S_; k0 += 16) {
    float4 a  = *(const float4*)(P + k0);
    float4 v4 = *(const float4*)(V + (size_t)k0 * LDQKV);
    As[lc+0][lr] = a.x; As[lc+1][lr] = a.y; As[lc+2][lr] = a.z; As[lc+3][lr] = a.w;
    *(float4*)&Bs[t >> 4][(t & 15) << 2] = v4;
    __syncthreads();
    #pragma unroll
    for (int kk = 0; kk < 16; ++kk) {
      float av[4], bv[4];
      *(float4*)av = *(const float4*)&As[kk][tr*4];
      *(float4*)bv = *(const float4*)&Bs[kk][tc*4];
      #pragma unroll
      for (int i = 0; i < 4; ++i)
        #pragma unroll
        for (int j = 0; j < 4; ++j)
          acc[i][j] = fmaf(av[i], bv[j], acc[i][j]);
    }
    __syncthreads();
  }

  #pragma unroll
  for (int i = 0; i < 4; ++i) {
    const int qi = qi0 + tr*4 + i;
    f16* orow = (f16*)(qkv + (size_t)(b * S_ + qi) * LDQKV) + h * HD_ + n0 + tc*4;
    f16x4 v;
    float xs;
    xs = fminf(fmaxf(acc[i][0] / s, 0.0f), 255.0f); v.x = (f16)rintf(xs);
    xs = fminf(fmaxf(acc[i][1] / s, 0.0f), 255.0f); v.y = (f16)rintf(xs);
    xs = fminf(fmaxf(acc[i][2] / s, 0.0f), 255.0f); v.z = (f16)rintf(xs);
    xs = fminf(fmaxf(acc[i][3] / s, 0.0f), 255.0f); v.w = (f16)rintf(xs);
    *(f16x4*)orow = v;
  }
}

extern "C" void kernel_launch(void* const* d_in, const int* in_sizes, int n_in,
                              void* d_out, int out_size, void* d_ws, size_t ws_size,
                              hipStream_t stream)
{
  const float* hidden = (const float*)d_in[0];
  const float* cosp   = (const float*)d_in[1];
  const float* sinp   = (const float*)d_in[2];
  const float* mask   = (const float*)d_in[3];
  const float* Wq     = (const float*)d_in[4];
  const float* Wk     = (const float*)d_in[5];
  const float* Wv     = (const float*)d_in[6];
  const float* Wo     = (const float*)d_in[7];
  const float* s_q    = (const float*)d_in[8];
  const float* s_k    = (const float*)d_in[9];
  const float* s_v    = (const float*)d_in[10];
  const float* s_attn = (const float*)d_in[11];
  const float* s_after= (const float*)d_in[12];
  const float* s_o    = (const float*)d_in[13];

  float* out  = (float*)d_out;                 // (B,S,H) f32
  float* attn = out + (size_t)M_ * H_;         // (B,NH,S,S) f32 — scratch until scores
  float* qkv  = (float*)d_ws;                  // [M_][6144] f32, 100.7 MB
  f16*  f16qkv = (f16*)qkv;                    // f16 view, 12288 per row

  // phase-1 scratch inside the (not-yet-written) attn region: 134 MB of 537
  f16* scr = (f16*)attn;
  f16* hHi = scr;
  f16* hLo = scr + (size_t)16777216;
  f16* wHi = scr + (size_t)2 * 16777216;
  f16* wLo = scr + (size_t)3 * 16777216;

  dim3 blk(256, 1, 1);

  // 1) pre-split hidden + weights; QKV projections via MFMA gemm (3-term)
  split_flat<<<dim3(16384), blk, 0, stream>>>(hidden, hHi, hLo);
  split_flat<<<dim3(16384), blk, 0, stream>>>(Wq, wHi, wLo);
  gemm_mfma<2,0><<<dim3(32,16), blk, 0, stream>>>(hHi, hLo, H_, wHi, wLo, H_,
                                                  qkv,        LDQKV, H_, nullptr, nullptr);
  split_flat<<<dim3(4096), blk, 0, stream>>>(Wk, wHi, wLo);
  gemm_mfma<2,0><<<dim3(8,16),  blk, 0, stream>>>(hHi, hLo, H_, wHi, wLo, H_,
                                                  qkv + H_,   LDQKV, H_, nullptr, nullptr);
  split_flat<<<dim3(4096), blk, 0, stream>>>(Wv, wHi, wLo);
  gemm_mfma<2,0><<<dim3(8,16),  blk, 0, stream>>>(hHi, hLo, H_, wHi, wLo, H_,
                                                  qkv + VOFF, LDQKV, H_, nullptr, nullptr);

  // 2) quantize + RoPE (q,k), quantize (v) — in place, f32
  quant_rope<<<dim3(M_*NH_*64/256),  blk, 0, stream>>>(qkv, 0,  NH_,  cosp, sinp, s_q);
  quant_rope<<<dim3(M_*NKV_*64/256), blk, 0, stream>>>(qkv, H_, NKV_, cosp, sinp, s_k);
  quant_v   <<<dim3(M_*1024/256),    blk, 0, stream>>>(qkv, s_v);

  // 3) scores -> quant -> +mask -> softmax (in d_out attn region)
  scores_kernel <<<dim3(256, NH_, B_), blk, 0, stream>>>(qkv, mask, attn, s_attn);
  softmax_kernel<<<dim3(B_*NH_*S_),    blk, 0, stream>>>(attn);

  // 4) PV -> quantized INT stored as exact f16 into f16qkv cols [0,4096)
  pv_kernel<<<dim3(32, NH_, B_), blk, 0, stream>>>(attn, qkv, s_after);

  // 5) Wo split into dead f16 cols [4096,12288); final GEMM (2-term, A exact int)
  split_wo<<<dim3(16384), blk, 0, stream>>>(Wo, f16qkv);
  gemm_mfma<1,1><<<dim3(32,16), blk, 0, stream>>>(f16qkv, nullptr, LDF16,
                                                  f16qkv + 4096, f16qkv + 8192, LDF16,
                                                  out, H_, H_, s_after, s_o);
}

// Round 7
// 1841.345 us; speedup vs baseline: 2.9787x; 1.2636x over previous
//
#include <hip/hip_runtime.h>
#include <math.h>

// Problem constants (B,S,H)=(4,1024,4096), NH=32, NKV=8, HD=128, LEVEL=256
#define B_   4
#define S_   1024
#define H_   4096
#define NH_  32
#define NKV_ 8
#define HD_  128
#define M_   (B_*S_)          // 4096 rows (b*S+s)
#define LDF16 12288           // f16 slots per ws row
#define SCALING 0.08838834764831845f  // HD**-0.5

// ws f16 row layout (per row m = b*S+s), 12288 slots = 24 KB/row, 100.7 MB total:
//   [0,4096)      qhi   (permuted rope dims)   -> after attn: PVint (exact int f16)
//   [4096,8192)   qlo                          -> after pv:   Wo hi
//   [8192,9216)   khi   (permuted)             -> after pv:   Wo lo (part)
//   [9216,10240)  klo                          -> Wo lo (part)
//   [10240,11264) unused                       -> Wo lo (part)
//   [11264,12288) Vt    (flat f-index space)   -> Wo lo (part)

typedef _Float16 f16;
typedef __attribute__((ext_vector_type(4))) _Float16 f16x4;
typedef __attribute__((ext_vector_type(8))) _Float16 f16x8;
typedef __attribute__((ext_vector_type(4))) float f32x4;

__device__ __forceinline__ float lsq_sym(float x, float s) {
  float xs = x / s;
  xs = fminf(fmaxf(xs, -128.0f), 127.0f);
  return rintf(xs) * s;
}
__device__ __forceinline__ float lsq_asym(float x, float s) {
  float xs = x / s;
  xs = fminf(fmaxf(xs, 0.0f), 255.0f);
  return rintf(xs) * s;
}

struct f16pair { f16 hi, lo; };
__device__ __forceinline__ f16pair cvt_hilo(float x) {
  f16pair r;
  r.hi = (f16)x;
  r.lo = (f16)(x - (float)r.hi);
  return r;
}

__device__ __forceinline__ void gload16(const void* g, void* l) {
  __builtin_amdgcn_global_load_lds((const __attribute__((address_space(1))) void*)g,
                                   (__attribute__((address_space(3))) void*)l, 16, 0, 0);
}

// ---------------------------------------------------------------------------
// splits
// ---------------------------------------------------------------------------
__global__ __launch_bounds__(256)
void split_flat(const float* __restrict__ src, f16* __restrict__ hi, f16* __restrict__ lo)
{
  const size_t i = ((size_t)blockIdx.x * 256 + threadIdx.x) * 4;
  float4 v = *(const float4*)(src + i);
  f16x4 h, l; f16pair p;
  p = cvt_hilo(v.x); h.x = p.hi; l.x = p.lo;
  p = cvt_hilo(v.y); h.y = p.hi; l.y = p.lo;
  p = cvt_hilo(v.z); h.z = p.hi; l.z = p.lo;
  p = cvt_hilo(v.w); h.w = p.hi; l.w = p.lo;
  *(f16x4*)(hi + i) = h;
  *(f16x4*)(lo + i) = l;
}

// W rows permuted so RoPE pair (d, d+64) lands on adjacent output slots (2d, 2d+1)
__global__ __launch_bounds__(256)
void split_wqk(const float* __restrict__ W, f16* __restrict__ hi, f16* __restrict__ lo, int ldw)
{
  const size_t i = ((size_t)blockIdx.x * 256 + threadIdx.x) * 4;
  const int n = (int)(i / ldw);
  const int k = (int)(i % ldw);
  const int d = n & 127;
  const int prow = (n & ~127) | ((d < 64) ? (d << 1) : (((d - 64) << 1) | 1));
  float4 v = *(const float4*)(W + i);
  f16x4 h, l; f16pair p;
  p = cvt_hilo(v.x); h.x = p.hi; l.x = p.lo;
  p = cvt_hilo(v.y); h.y = p.hi; l.y = p.lo;
  p = cvt_hilo(v.z); h.z = p.hi; l.z = p.lo;
  p = cvt_hilo(v.w); h.w = p.hi; l.w = p.lo;
  *(f16x4*)(hi + (size_t)prow * ldw + k) = h;
  *(f16x4*)(lo + (size_t)prow * ldw + k) = l;
}

// Wo hi/lo into dead ws slots: hi at 4096, lo at 8192
__global__ __launch_bounds__(256)
void split_wo(const float* __restrict__ Wo, f16* __restrict__ base)
{
  const size_t i = ((size_t)blockIdx.x * 256 + threadIdx.x) * 4;
  const int n = (int)(i >> 12);
  const int k = (int)(i & 4095);
  float4 v = *(const float4*)(Wo + i);
  f16x4 h, l; f16pair p;
  p = cvt_hilo(v.x); h.x = p.hi; l.x = p.lo;
  p = cvt_hilo(v.y); h.y = p.hi; l.y = p.lo;
  p = cvt_hilo(v.z); h.z = p.hi; l.z = p.lo;
  p = cvt_hilo(v.w); h.w = p.hi; l.w = p.lo;
  f16* rp = base + (size_t)n * LDF16;
  *(f16x4*)(rp + 4096 + k) = h;
  *(f16x4*)(rp + 8192 + k) = l;
}

// ---------------------------------------------------------------------------
// MFMA GEMM (256x128 tile, 4 waves, BK=32, global_load_lds staging) — as r6.
// EPI 1: C[gr][gc] = lsq_sym(acc * (*sA), *sQ)              (final out GEMM)
// EPI 2: quant(lsq_sym,*sA) -> RoPE (adjacent-pair shfl) -> hi/lo f16 to ws
// EPI 3: Vint = round(clip(acc/(*sA))) exact f16, stored TRANSPOSED (Vt)
// ---------------------------------------------------------------------------
template<int ATERMS, int EPI>
__global__ __launch_bounds__(256, 2)
void gemm_mfma(const f16* __restrict__ Ahi, const f16* __restrict__ Alo, int lda,
               const f16* __restrict__ Bhi, const f16* __restrict__ Blo, int ldb,
               float* __restrict__ C, int ldc, int K,
               const float* __restrict__ sA, const float* __restrict__ sQ,
               const float* __restrict__ cosp, const float* __restrict__ sinp,
               f16* __restrict__ oBase, int hiOff, int loOff)
{
  __shared__ f16 sAh[256 * 32];
  __shared__ f16 sAl[(ATERMS == 2) ? 256 * 32 : 64];
  __shared__ f16 sBh[128 * 32];
  __shared__ f16 sBl[128 * 32];

  const int m0 = blockIdx.y << 8;
  const int n0 = blockIdx.x << 7;
  const int t    = threadIdx.x;
  const int lane = t & 63;
  const int wv   = t >> 6;
  const int wm   = (wv >> 1) << 7;
  const int wn   = (wv & 1) << 6;
  const int lrow = lane & 15;
  const int kg   = (lane >> 4) << 3;
  const int fsw  = (lrow & 3) << 3;

  const int sr   = lane >> 2;
  const int slot = lane & 3;
  const int kcs  = ((slot ^ (sr & 3)) << 3);

  f32x4 acc[8][4];
  #pragma unroll
  for (int i = 0; i < 8; ++i)
    #pragma unroll
    for (int j = 0; j < 4; ++j) acc[i][j] = (f32x4){0.f, 0.f, 0.f, 0.f};

  for (int k0 = 0; k0 < K; k0 += 32) {
    #pragma unroll
    for (int i = 0; i < 4; ++i) {
      const int rowb = (wv << 6) + (i << 4);
      const size_t goff = (size_t)(m0 + rowb + sr) * lda + k0 + kcs;
      gload16(Ahi + goff, &sAh[rowb * 32]);
      if constexpr (ATERMS == 2) gload16(Alo + goff, &sAl[rowb * 32]);
    }
    #pragma unroll
    for (int i = 0; i < 2; ++i) {
      const int rowb = (wv << 5) + (i << 4);
      const size_t goff = (size_t)(n0 + rowb + sr) * ldb + k0 + kcs;
      gload16(Bhi + goff, &sBh[rowb * 32]);
      gload16(Blo + goff, &sBl[rowb * 32]);
    }
    __syncthreads();

    f16x8 a[8], bh[4], bl[4];
    #pragma unroll
    for (int j = 0; j < 4; ++j) {
      const int r = wn + (j << 4) + lrow;
      bh[j] = *(const f16x8*)&sBh[r * 32 + (kg ^ fsw)];
      bl[j] = *(const f16x8*)&sBl[r * 32 + (kg ^ fsw)];
    }
    #pragma unroll
    for (int i = 0; i < 8; ++i)
      a[i] = *(const f16x8*)&sAh[(wm + (i << 4) + lrow) * 32 + (kg ^ fsw)];
    #pragma unroll
    for (int i = 0; i < 8; ++i)
      #pragma unroll
      for (int j = 0; j < 4; ++j) {
        acc[i][j] = __builtin_amdgcn_mfma_f32_16x16x32_f16(a[i], bh[j], acc[i][j], 0, 0, 0);
        acc[i][j] = __builtin_amdgcn_mfma_f32_16x16x32_f16(a[i], bl[j], acc[i][j], 0, 0, 0);
      }
    if constexpr (ATERMS == 2) {
      #pragma unroll
      for (int i = 0; i < 8; ++i)
        a[i] = *(const f16x8*)&sAl[(wm + (i << 4) + lrow) * 32 + (kg ^ fsw)];
      #pragma unroll
      for (int i = 0; i < 8; ++i)
        #pragma unroll
        for (int j = 0; j < 4; ++j)
          acc[i][j] = __builtin_amdgcn_mfma_f32_16x16x32_f16(a[i], bh[j], acc[i][j], 0, 0, 0);
    }
    __syncthreads();
  }

  const float s = *sA;
  float sQv = 1.0f;
  if constexpr (EPI == 1) sQv = *sQ;

  #pragma unroll
  for (int i = 0; i < 8; ++i)
    #pragma unroll
    for (int j = 0; j < 4; ++j) {
      const int gc = n0 + wn + (j << 4) + lrow;
      #pragma unroll
      for (int r = 0; r < 4; ++r) {
        const int gr = m0 + wm + (i << 4) + ((lane >> 4) << 2) + r;
        float x = acc[i][j][r];
        if constexpr (EPI == 1) {
          C[(size_t)gr * ldc + gc] = lsq_sym(x * s, sQv);
        } else if constexpr (EPI == 2) {
          float qv = lsq_sym(x, s);
          float pv = __shfl_xor(qv, 1);
          const int dpair = (gc & 127) >> 1;
          float cs = cosp[(size_t)gr * HD_ + dpair];
          float sn = sinp[(size_t)gr * HD_ + dpair];
          float ro = (gc & 1) ? (qv * cs + pv * sn) : (qv * cs - pv * sn);
          f16pair hp = cvt_hilo(ro);
          f16* o = oBase + (size_t)gr * LDF16;
          o[hiOff + gc] = hp.hi;
          o[loOff + gc] = hp.lo;
        } else { // EPI == 3: Vt, exact int f16
          float xi = rintf(fminf(fmaxf(x / s, -128.0f), 127.0f));
          const int bb = gr >> 10, ss = gr & 1023;
          const int kv = gc >> 7,  dd = gc & 127;
          const size_t f = ((size_t)((bb * 8 + kv) * 128 + dd) << 10) + ss;
          oBase[(f >> 10) * LDF16 + 11264 + (f & 1023)] = (f16)xi;
        }
      }
    }
}

// ---------------------------------------------------------------------------
// Fused scores + quant + causal mask + softmax. 16 q-rows/block, 4 waves,
// wave w owns ki in [w*256, w*256+256) (16 tiles). Logits live in MFMA accs.
// Writes final probs f32 to d_out attn. Fully-masked tiles skip loads+MFMA.
// ---------------------------------------------------------------------------
__global__ __launch_bounds__(256)
void attn_fused(const f16* __restrict__ fqkv, float* __restrict__ attn,
                const float* __restrict__ saP)
{
  const int b = blockIdx.z, h = blockIdx.y, qi0 = blockIdx.x << 4;
  const int t = threadIdx.x, lane = t & 63, w = t >> 6;
  const int lc = lane & 15, lg = lane >> 4;
  const int kvh = h >> 2;
  const float sa = *saP;

  f16x8 qh[4], ql[4];
  {
    const f16* qrow = fqkv + (size_t)(b * S_ + qi0 + lc) * LDF16 + h * HD_;
    #pragma unroll
    for (int c = 0; c < 4; ++c) {
      const int off = c * 32 + lg * 8;
      qh[c] = *(const f16x8*)(qrow + off);
      ql[c] = *(const f16x8*)(qrow + 4096 + off);
    }
  }

  f32x4 acc[16];
  #pragma unroll
  for (int tt = 0; tt < 16; ++tt) acc[tt] = (f32x4){0.f, 0.f, 0.f, 0.f};

  const int qimax = qi0 + 15;
  const f16* kbase = fqkv + (size_t)(b * S_) * LDF16 + 8192 + kvh * HD_;

  #pragma unroll
  for (int tt = 0; tt < 16; ++tt) {
    const int ki0 = (w << 8) + (tt << 4);
    if (ki0 <= qimax) {
      const f16* krow = kbase + (size_t)(ki0 + lc) * LDF16;
      #pragma unroll
      for (int c = 0; c < 4; ++c) {
        const int off = c * 32 + lg * 8;
        f16x8 kh = *(const f16x8*)(krow + off);
        f16x8 kl = *(const f16x8*)(krow + 1024 + off);
        acc[tt] = __builtin_amdgcn_mfma_f32_16x16x32_f16(qh[c], kh, acc[tt], 0, 0, 0);
        acc[tt] = __builtin_amdgcn_mfma_f32_16x16x32_f16(ql[c], kh, acc[tt], 0, 0, 0);
        acc[tt] = __builtin_amdgcn_mfma_f32_16x16x32_f16(qh[c], kl, acc[tt], 0, 0, 0);
      }
    }
  }

  // quant + causal mask + row max
  float m4[4] = {-3.0e38f, -3.0e38f, -3.0e38f, -3.0e38f};
  #pragma unroll
  for (int tt = 0; tt < 16; ++tt) {
    const int ki = (w << 8) + (tt << 4) + lc;
    #pragma unroll
    for (int r = 0; r < 4; ++r) {
      const int qi = qi0 + lg * 4 + r;
      float x = (ki <= qi) ? lsq_asym(acc[tt][r] * SCALING, sa) : -3.0e38f;
      acc[tt][r] = x;
      m4[r] = fmaxf(m4[r], x);
    }
  }
  #pragma unroll
  for (int off = 1; off < 16; off <<= 1)
    #pragma unroll
    for (int r = 0; r < 4; ++r) m4[r] = fmaxf(m4[r], __shfl_xor(m4[r], off));

  __shared__ float red[4][16];
  if (lc == 0) {
    #pragma unroll
    for (int r = 0; r < 4; ++r) red[w][lg * 4 + r] = m4[r];
  }
  __syncthreads();
  float mrow[4];
  #pragma unroll
  for (int r = 0; r < 4; ++r) {
    const int row = lg * 4 + r;
    mrow[r] = fmaxf(fmaxf(red[0][row], red[1][row]), fmaxf(red[2][row], red[3][row]));
  }
  __syncthreads();

  // exp + row sum
  float s4[4] = {0.f, 0.f, 0.f, 0.f};
  #pragma unroll
  for (int tt = 0; tt < 16; ++tt)
    #pragma unroll
    for (int r = 0; r < 4; ++r) {
      float p = expf(acc[tt][r] - mrow[r]);
      acc[tt][r] = p;
      s4[r] += p;
    }
  #pragma unroll
  for (int off = 1; off < 16; off <<= 1)
    #pragma unroll
    for (int r = 0; r < 4; ++r) s4[r] += __shfl_xor(s4[r], off);
  if (lc == 0) {
    #pragma unroll
    for (int r = 0; r < 4; ++r) red[w][lg * 4 + r] = s4[r];
  }
  __syncthreads();
  float inv[4];
  #pragma unroll
  for (int r = 0; r < 4; ++r) {
    const int row = lg * 4 + r;
    inv[r] = 1.0f / (red[0][row] + red[1][row] + red[2][row] + red[3][row]);
  }

  // store probs
  #pragma unroll
  for (int tt = 0; tt < 16; ++tt) {
    const int ki = (w << 8) + (tt << 4) + lc;
    #pragma unroll
    for (int r = 0; r < 4; ++r) {
      const int qi = qi0 + lg * 4 + r;
      attn[((size_t)(b * NH_ + h) * S_ + qi) * S_ + ki] = acc[tt][r] * inv[r];
    }
  }
}

// ---------------------------------------------------------------------------
// PV via MFMA, computing D'[d][q] = sum_ki Vt[d][ki] * P[q][ki]  (= (P·V)^T).
// A = Vt (exact int f16, 1 term); B = P rows, hi/lo split in-regs (2 terms).
// Epilogue: PVint = round(clip(s_v*acc/s_after,0,255)) exact f16 -> ws[0,4096).
// ---------------------------------------------------------------------------
__global__ __launch_bounds__(256)
void pv_mfma(const float* __restrict__ attn, f16* __restrict__ fqkv,
             const float* __restrict__ svP, const float* __restrict__ safP)
{
  const int b = blockIdx.z, h = blockIdx.y, q0 = blockIdx.x << 7;
  const int t = threadIdx.x, lane = t & 63, w = t >> 6;
  const int wd = (w >> 1) << 6, wq = (w & 1) << 6;
  const int lc = lane & 15, lg = lane >> 4;
  const int kvh = h >> 2;
  const float sv = *svP, saf = *safP;

  f32x4 acc[4][4];
  #pragma unroll
  for (int i = 0; i < 4; ++i)
    #pragma unroll
    for (int j = 0; j < 4; ++j) acc[i][j] = (f32x4){0.f, 0.f, 0.f, 0.f};

  const float* Pbase = attn + (size_t)(b * NH_ + h) * S_ * S_;
  const int kimax = q0 + 128;

  for (int ki0 = 0; ki0 < kimax; ki0 += 32) {
    f16x8 a[4];
    #pragma unroll
    for (int i = 0; i < 4; ++i) {
      const int d = wd + i * 16 + lc;
      const size_t f = ((size_t)((b * 8 + kvh) * 128 + d) << 10) + ki0 + lg * 8;
      a[i] = *(const f16x8*)(fqkv + (f >> 10) * LDF16 + 11264 + (f & 1023));
    }
    #pragma unroll
    for (int j = 0; j < 4; ++j) {
      const int q = q0 + wq + j * 16 + lc;
      const float* pp = Pbase + (size_t)q * S_ + ki0 + lg * 8;
      float4 p0 = *(const float4*)pp;
      float4 p1 = *(const float4*)(pp + 4);
      f16x8 bh, bl; f16pair pr;
      pr = cvt_hilo(p0.x); bh[0] = pr.hi; bl[0] = pr.lo;
      pr = cvt_hilo(p0.y); bh[1] = pr.hi; bl[1] = pr.lo;
      pr = cvt_hilo(p0.z); bh[2] = pr.hi; bl[2] = pr.lo;
      pr = cvt_hilo(p0.w); bh[3] = pr.hi; bl[3] = pr.lo;
      pr = cvt_hilo(p1.x); bh[4] = pr.hi; bl[4] = pr.lo;
      pr = cvt_hilo(p1.y); bh[5] = pr.hi; bl[5] = pr.lo;
      pr = cvt_hilo(p1.z); bh[6] = pr.hi; bl[6] = pr.lo;
      pr = cvt_hilo(p1.w); bh[7] = pr.hi; bl[7] = pr.lo;
      #pragma unroll
      for (int i = 0; i < 4; ++i) {
        acc[i][j] = __builtin_amdgcn_mfma_f32_16x16x32_f16(a[i], bh, acc[i][j], 0, 0, 0);
        acc[i][j] = __builtin_amdgcn_mfma_f32_16x16x32_f16(a[i], bl, acc[i][j], 0, 0, 0);
      }
    }
  }

  #pragma unroll
  for (int i = 0; i < 4; ++i)
    #pragma unroll
    for (int j = 0; j < 4; ++j) {
      const int q  = q0 + wq + j * 16 + lc;
      const int d0 = wd + i * 16 + lg * 4;
      f16x4 v;
      #pragma unroll
      for (int r = 0; r < 4; ++r) {
        float x = sv * acc[i][j][r];
        x = fminf(fmaxf(x / saf, 0.0f), 255.0f);
        v[r] = (f16)rintf(x);
      }
      *(f16x4*)(fqkv + (size_t)(b * S_ + q) * LDF16 + h * HD_ + d0) = v;
    }
}

extern "C" void kernel_launch(void* const* d_in, const int* in_sizes, int n_in,
                              void* d_out, int out_size, void* d_ws, size_t ws_size,
                              hipStream_t stream)
{
  const float* hidden = (const float*)d_in[0];
  const float* cosp   = (const float*)d_in[1];
  const float* sinp   = (const float*)d_in[2];
  const float* Wq     = (const float*)d_in[4];
  const float* Wk     = (const float*)d_in[5];
  const float* Wv     = (const float*)d_in[6];
  const float* Wo     = (const float*)d_in[7];
  const float* s_q    = (const float*)d_in[8];
  const float* s_k    = (const float*)d_in[9];
  const float* s_v    = (const float*)d_in[10];
  const float* s_attn = (const float*)d_in[11];
  const float* s_after= (const float*)d_in[12];
  const float* s_o    = (const float*)d_in[13];

  float* out  = (float*)d_out;                 // (B,S,H) f32
  float* attn = out + (size_t)M_ * H_;         // (B,NH,S,S) f32 — written by attn_fused
  f16*  f16qkv = (f16*)d_ws;                   // [M_][12288] f16, 100.7 MB

  // split scratch inside the not-yet-written attn region (134 MB of 537)
  f16* scr = (f16*)attn;
  f16* hHi = scr;
  f16* hLo = scr + (size_t)16777216;
  f16* wHi = scr + (size_t)2 * 16777216;
  f16* wLo = scr + (size_t)3 * 16777216;

  dim3 blk(256, 1, 1);

  // 1) hidden split; Q/K projections with fused quant+RoPE epilogue (permuted W rows)
  split_flat<<<dim3(16384), blk, 0, stream>>>(hidden, hHi, hLo);
  split_wqk<<<dim3(16384), blk, 0, stream>>>(Wq, wHi, wLo, H_);
  gemm_mfma<2,2><<<dim3(32,16), blk, 0, stream>>>(hHi, hLo, H_, wHi, wLo, H_,
      nullptr, 0, H_, s_q, nullptr, cosp, sinp, f16qkv, 0, 4096);
  split_wqk<<<dim3(4096), blk, 0, stream>>>(Wk, wHi, wLo, H_);
  gemm_mfma<2,2><<<dim3(8,16), blk, 0, stream>>>(hHi, hLo, H_, wHi, wLo, H_,
      nullptr, 0, H_, s_k, nullptr, cosp, sinp, f16qkv, 8192, 9216);

  // 2) V projection with fused quant -> transposed exact-int f16 (Vt)
  split_flat<<<dim3(4096), blk, 0, stream>>>(Wv, wHi, wLo);
  gemm_mfma<2,3><<<dim3(8,16), blk, 0, stream>>>(hHi, hLo, H_, wHi, wLo, H_,
      nullptr, 0, H_, s_v, nullptr, nullptr, nullptr, f16qkv, 0, 0);

  // 3) fused scores+quant+mask+softmax -> probs straight to d_out
  attn_fused<<<dim3(64, NH_, B_), blk, 0, stream>>>(f16qkv, attn, s_attn);

  // 4) PV (MFMA) -> PVint exact f16 into dead qhi slots [0,4096)
  pv_mfma<<<dim3(8, NH_, B_), blk, 0, stream>>>(attn, f16qkv, s_v, s_after);

  // 5) Wo split into dead slots; final GEMM (1-term exact A) + lsq_sym epilogue
  split_wo<<<dim3(16384), blk, 0, stream>>>(Wo, f16qkv);
  gemm_mfma<1,1><<<dim3(32,16), blk, 0, stream>>>(f16qkv, nullptr, LDF16,
      f16qkv + 4096, f16qkv + 8192, LDF16,
      out, H_, H_, s_after, s_o, nullptr, nullptr, nullptr, 0, 0);
}